// Round 1
// baseline (3526.917 us; speedup 1.0000x reference)
//
#include <hip/hip_runtime.h>
#include <cmath>

#define EPSF 1e-8f

// Problem constants (fixed by setup_inputs)
// B=1024 rows, D=256 dims, S=65536 slots, K=16

__device__ __forceinline__ bool better(float v1, int i1, float v2, int i2) {
  // top-k order: larger value wins; tie -> smaller index (matches lax.top_k)
  return (v1 > v2) || (v1 == v2 && i1 < i2);
}

__device__ __forceinline__ float block_sum256(float x, float* red) {
  #pragma unroll
  for (int m = 1; m < 64; m <<= 1) x += __shfl_xor(x, m);
  __syncthreads();
  if ((threadIdx.x & 63) == 0) red[threadIdx.x >> 6] = x;
  __syncthreads();
  return red[0] + red[1] + red[2] + red[3];
}

// ---------------------------------------------------------------------------
// K1: normalize key/value/query, circular-convolve (HRR bind), store
//   Qall[0..1023]    = normalize(normalize(key))    (write-ranking queries)
//   Qall[1024..2047] = normalize(normalize(query))  (read-ranking queries)
//   qn1              = normalize(query)             (for unbind)
//   bound            = circconv(key_n, val_n)
// ---------------------------------------------------------------------------
__global__ void prep_kernel(const float* __restrict__ key, const float* __restrict__ value,
                            const float* __restrict__ query, float* __restrict__ Qall,
                            float* __restrict__ qn1, float* __restrict__ bound) {
  const int b = blockIdx.x, t = threadIdx.x;
  __shared__ float kn[256], vn[256], red[4];
  const float kv = key[(size_t)b * 256 + t];
  const float vv = value[(size_t)b * 256 + t];
  const float qv = query[(size_t)b * 256 + t];
  const float sk = block_sum256(kv * kv, red);
  const float sv = block_sum256(vv * vv, red);
  const float sq = block_sum256(qv * qv, red);
  const float knv = kv / (sqrtf(sk) + EPSF);
  const float vnv = vv / (sqrtf(sv) + EPSF);
  const float qnv = qv / (sqrtf(sq) + EPSF);
  kn[t] = knv; vn[t] = vnv;
  qn1[(size_t)b * 256 + t] = qnv;
  // reference re-normalizes inside _topk_idx -> replicate double-normalize
  const float sk2 = block_sum256(knv * knv, red);
  const float sq2 = block_sum256(qnv * qnv, red);
  Qall[(size_t)b * 256 + t] = knv / (sqrtf(sk2) + EPSF);
  Qall[(size_t)(1024 + b) * 256 + t] = qnv / (sqrtf(sq2) + EPSF);
  __syncthreads();
  // bound[i] = sum_j kn[j] * vn[(i-j) mod 256]  == irfft(rfft(kn)*rfft(vn))
  float acc = 0.f;
  for (int j = 0; j < 256; ++j) acc += kn[j] * vn[(t - j) & 255];
  bound[(size_t)b * 256 + t] = acc;
}

// ---------------------------------------------------------------------------
// K2: similarities + per-chunk top-16.
// Grid: 32 row-tiles (64 rows) x 8 slot chunks (8192 slots) = 256 blocks.
// Block: 256 threads = 4 waves; wave = row-group of 16 rows.
// Thread: 4 slots x 16 rows fp32 accumulators; Q tile in LDS (64KB),
// top-16 lists held in wave-distributed registers (no LDS hazards).
// ---------------------------------------------------------------------------
__launch_bounds__(256)
__global__ void sims_topk_kernel(const float* __restrict__ Qall,
                                 const float* __restrict__ addr,
                                 float* __restrict__ pv, int* __restrict__ pi) {
  constexpr int CH = 8192;      // slots per chunk
  constexpr int NIT = CH / 256; // 32 iterations of 256 slots
  const int bx = blockIdx.x;
  const int chunk = bx >> 5;    // 0..7
  const int rt = bx & 31;       // row tile 0..31
  const int t = threadIdx.x;
  const int lane = t & 63;
  const int rg = t >> 6;        // wave id == row group
  const int lane16 = lane & 15;
  const int grp = lane >> 4;

  __shared__ float Q[64 * 256]; // 64 KB exactly

  {
    const float4* src = (const float4*)(Qall + (size_t)(rt * 64) * 256);
    float4* dst = (float4*)Q;
    #pragma unroll
    for (int i = 0; i < 16; ++i) dst[i * 256 + t] = src[i * 256 + t];
  }
  __syncthreads();

  // per-row (16 rows of this wave) running threshold = current worst of top-16
  float thrV[16]; int thrI[16];
  // distributed top-16 lists: row r lives in lane group (r>>2); this lane
  // holds entry k=lane16 for rows r with r>>2 == grp, in eV/eI[r&3].
  float eV[4]; int eI[4];
  #pragma unroll
  for (int r = 0; r < 16; ++r) { thrV[r] = -INFINITY; thrI[r] = 0x7FFFFFFF; }
  #pragma unroll
  for (int j = 0; j < 4; ++j) { eV[j] = -INFINITY; eI[j] = 0x7FFFFFFF; }

  const int cbase = chunk * CH;
  for (int it = 0; it < NIT; ++it) {
    const int sbase = cbase + it * 256;
    const float* ap = addr + (size_t)(sbase + lane) * 256;
    float acc[4][16];
    float an[4];
    #pragma unroll
    for (int j = 0; j < 4; ++j) {
      an[j] = 0.f;
      #pragma unroll
      for (int r = 0; r < 16; ++r) acc[j][r] = 0.f;
    }
    for (int d4 = 0; d4 < 64; ++d4) {
      float4 a[4];
      #pragma unroll
      for (int j = 0; j < 4; ++j) a[j] = *(const float4*)(ap + j * (64 * 256) + d4 * 4);
      #pragma unroll
      for (int j = 0; j < 4; ++j)
        an[j] += a[j].x * a[j].x + a[j].y * a[j].y + a[j].z * a[j].z + a[j].w * a[j].w;
      #pragma unroll
      for (int r = 0; r < 16; ++r) {
        const float4 q = *(const float4*)&Q[(rg * 16 + r) * 256 + d4 * 4];
        #pragma unroll
        for (int j = 0; j < 4; ++j)
          acc[j][r] += a[j].x * q.x + a[j].y * q.y + a[j].z * q.z + a[j].w * q.w;
      }
    }
    float dn[4];
    #pragma unroll
    for (int j = 0; j < 4; ++j) dn[j] = sqrtf(an[j]) + EPSF; // address norm (+eps)

    #pragma unroll
    for (int r = 0; r < 16; ++r) {
      const int g = r >> 2;
      float c[4]; int ci[4];
      #pragma unroll
      for (int j = 0; j < 4; ++j) { c[j] = acc[j][r] / dn[j]; ci[j] = sbase + j * 64 + lane; }
      while (true) {
        float bv = c[0]; int bi = ci[0];
        #pragma unroll
        for (int j = 1; j < 4; ++j) if (better(c[j], ci[j], bv, bi)) { bv = c[j]; bi = ci[j]; }
        const bool cand = better(bv, bi, thrV[r], thrI[r]);
        if (__ballot(cand) == 0ull) break;   // fast path: nothing beats threshold
        float wv = cand ? bv : -INFINITY; int wi = cand ? bi : 0x7FFFFFFF;
        #pragma unroll
        for (int m = 1; m < 64; m <<= 1) {
          const float ov = __shfl_xor(wv, m); const int oi = __shfl_xor(wi, m);
          if (better(ov, oi, wv, wi)) { wv = ov; wi = oi; }
        }
        // find worst entry of row r's list (within 16-lane group g); tie->lowest k
        float ev2 = eV[r & 3]; int ei2 = eI[r & 3]; int ek = lane16;
        #pragma unroll
        for (int m = 1; m < 16; m <<= 1) {
          const float ov = __shfl_xor(ev2, m); const int oi = __shfl_xor(ei2, m);
          const int ok = __shfl_xor(ek, m);
          const bool take = better(ev2, ei2, ov, oi) || (ev2 == ov && ei2 == oi && ok < ek);
          if (take) { ev2 = ov; ei2 = oi; ek = ok; }
        }
        const int wk = __shfl(ek, g * 16);
        if (grp == g && lane16 == wk) { eV[r & 3] = wv; eI[r & 3] = wi; }
        // recompute threshold (new worst) and broadcast to all lanes
        float nv = eV[r & 3]; int ni = eI[r & 3];
        #pragma unroll
        for (int m = 1; m < 16; m <<= 1) {
          const float ov = __shfl_xor(nv, m); const int oi = __shfl_xor(ni, m);
          if (better(nv, ni, ov, oi)) { nv = ov; ni = oi; }
        }
        thrV[r] = __shfl(nv, g * 16);
        thrI[r] = __shfl(ni, g * 16);
        // consume the inserted candidate (static indexing only)
        #pragma unroll
        for (int j = 0; j < 4; ++j) if (ci[j] == wi) c[j] = -INFINITY;
      }
    }
  }
  // write per-(row,chunk) partial top-16
  #pragma unroll
  for (int j = 0; j < 4; ++j) {
    const int rloc = grp * 4 + j;
    const int grow = rt * 64 + rg * 16 + rloc;
    pv[(size_t)grow * 128 + chunk * 16 + lane16] = eV[j];
    pi[(size_t)grow * 128 + chunk * 16 + lane16] = eI[j];
  }
}

// ---------------------------------------------------------------------------
// K3: merge 8 chunk-partials (128 candidates) -> final top-16 indices per row
// ---------------------------------------------------------------------------
__global__ void merge_topk_kernel(const float* __restrict__ pv, const int* __restrict__ pi,
                                  int* __restrict__ fidx) {
  const int row = blockIdx.x, t = threadIdx.x; // 128 threads = 2 waves
  float v = pv[(size_t)row * 128 + t];
  int idx = pi[(size_t)row * 128 + t];
  __shared__ float rv[2]; __shared__ int rix[2]; __shared__ int win;
  for (int s = 0; s < 16; ++s) {
    float wv = v; int wi = idx;
    #pragma unroll
    for (int m = 1; m < 64; m <<= 1) {
      const float ov = __shfl_xor(wv, m); const int oi = __shfl_xor(wi, m);
      if (better(ov, oi, wv, wi)) { wv = ov; wi = oi; }
    }
    if ((t & 63) == 0) { rv[t >> 6] = wv; rix[t >> 6] = wi; }
    __syncthreads();
    if (t == 0) {
      float fv = rv[0]; int fi = rix[0];
      if (better(rv[1], rix[1], fv, fi)) { fv = rv[1]; fi = rix[1]; }
      fidx[(size_t)row * 16 + s] = fi;
      win = fi;
    }
    __syncthreads();
    if (idx == win) v = -INFINITY; // slot ids unique across chunks
  }
}

// ---------------------------------------------------------------------------
// K4: content gather (decayed memory + write-hits via bitset join),
//     unbind via direct 256-pt DFT (Wiener division), normalize, store.
// ---------------------------------------------------------------------------
__global__ void finalize_kernel(const float* __restrict__ qn1,
                                const float* __restrict__ bound,
                                const int* __restrict__ fidx,
                                const float* __restrict__ mem,
                                float* __restrict__ out) {
  const int b = blockIdx.x, t = threadIdx.x;
  __shared__ unsigned int bs[2048];   // 65536-bit slot bitset
  __shared__ float cont[256], qn[256];
  __shared__ float Br[129], Bi[129];
  __shared__ float2 tw[256];          // cos/sin(2*pi*m/256)
  __shared__ int ri[16];
  __shared__ int hits[1024];
  __shared__ int hcnt;
  __shared__ float red[4];

  {
    const double ang = (6.283185307179586476925286766559 / 256.0) * (double)t;
    tw[t] = make_float2((float)cos(ang), (float)sin(ang));
  }
  #pragma unroll
  for (int i = 0; i < 8; ++i) bs[t + i * 256] = 0u;
  if (t == 0) hcnt = 0;
  qn[t] = qn1[(size_t)b * 256 + t];
  if (t < 16) ri[t] = fidx[(size_t)(1024 + b) * 16 + t]; // read slots
  __syncthreads();
  if (t < 16) atomicOr(&bs[ri[t] >> 5], 1u << (ri[t] & 31));
  __syncthreads();

  // decayed gather-sum of memory rows
  float c = 0.f;
  #pragma unroll
  for (int k = 0; k < 16; ++k) c += mem[(size_t)ri[k] * 256 + t];
  c *= 0.995f;

  // join against all 16384 write (row,slot) pairs
  for (int e = t; e < 16384; e += 256) {
    const int s = fidx[e]; // rows 0..1023 of fidx = idx_w
    if ((bs[s >> 5] >> (s & 31)) & 1u) {
      const int p = atomicAdd(&hcnt, 1);
      if (p < 1024) hits[p] = e;
    }
  }
  __syncthreads();
  int hn = hcnt; if (hn > 1024) hn = 1024;
  if (t == 0) { // sort for determinism (hn is tiny, ~4 expected)
    for (int i = 1; i < hn; ++i) {
      const int x = hits[i]; int j2 = i - 1;
      while (j2 >= 0 && hits[j2] > x) { hits[j2 + 1] = hits[j2]; --j2; }
      hits[j2 + 1] = x;
    }
  }
  __syncthreads();
  for (int h = 0; h < hn; ++h) c += bound[(size_t)(hits[h] >> 4) * 256 + t];
  cont[t] = c;
  __syncthreads();

  // forward rfft of qn and cont (direct DFT, 129 bins)
  if (t < 129) {
    float ar = 0.f, ai = 0.f, cr2 = 0.f, ci2 = 0.f;
    for (int n = 0; n < 256; ++n) {
      const float2 w = tw[(t * n) & 255];
      const float qv = qn[n], cv = cont[n];
      ar += qv * w.x; ai -= qv * w.y;
      cr2 += cv * w.x; ci2 -= cv * w.y;
    }
    const float den = ar * ar + ai * ai + 1e-8f; // |A|^2 + EPS
    Br[t] = (cr2 * ar + ci2 * ai) / den;         // C * conj(A) / den
    Bi[t] = (ci2 * ar - cr2 * ai) / den;
  }
  __syncthreads();

  // irfft (n=256)
  float o = Br[0] + ((t & 1) ? -Br[128] : Br[128]);
  for (int k = 1; k < 128; ++k) {
    const float2 w = tw[(k * t) & 255];
    o += 2.f * (Br[k] * w.x - Bi[k] * w.y);
  }
  o *= (1.f / 256.f);

  const float ss2 = block_sum256(o * o, red);
  out[(size_t)b * 256 + t] = o / (sqrtf(ss2) + EPSF);
}

// ---------------------------------------------------------------------------
extern "C" void kernel_launch(void* const* d_in, const int* in_sizes, int n_in,
                              void* d_out, int out_size, void* d_ws, size_t ws_size,
                              hipStream_t stream) {
  const float* key    = (const float*)d_in[0];
  const float* value  = (const float*)d_in[1];
  const float* query  = (const float*)d_in[2];
  const float* addr   = (const float*)d_in[3];
  const float* memory = (const float*)d_in[4];
  float* out = (float*)d_out;

  char* ws = (char*)d_ws;
  float* Qall  = (float*)(ws + 0);         // 2048*256*4 = 2 MB
  float* qn1   = (float*)(ws + 2097152);   // 1024*256*4 = 1 MB
  float* bound = (float*)(ws + 3145728);   // 1024*256*4 = 1 MB
  float* pv    = (float*)(ws + 4194304);   // 2048*128*4 = 1 MB
  int*   pi    = (int*)  (ws + 5242880);   // 1 MB
  int*   fidx  = (int*)  (ws + 6291456);   // 2048*16*4 = 128 KB

  prep_kernel<<<1024, 256, 0, stream>>>(key, value, query, Qall, qn1, bound);
  sims_topk_kernel<<<256, 256, 0, stream>>>(Qall, addr, pv, pi);
  merge_topk_kernel<<<2048, 128, 0, stream>>>(pv, pi, fidx);
  finalize_kernel<<<1024, 256, 0, stream>>>(qn1, bound, fidx, memory, out);
}

// Round 2
// 3069.287 us; speedup vs baseline: 1.1491x; 1.1491x over previous
//
#include <hip/hip_runtime.h>
#include <cmath>

#define EPSF 1e-8f

// Problem constants: B=1024 rows (x2 query sets), D=256 dims, S=65536 slots, K=16

__device__ __forceinline__ bool better(float v1, int i1, float v2, int i2) {
  // top-k order: larger value wins; tie -> smaller index (matches lax.top_k)
  return (v1 > v2) || (v1 == v2 && i1 < i2);
}

__device__ __forceinline__ float block_sum256(float x, float* red) {
  #pragma unroll
  for (int m = 1; m < 64; m <<= 1) x += __shfl_xor(x, m);
  __syncthreads();
  if ((threadIdx.x & 63) == 0) red[threadIdx.x >> 6] = x;
  __syncthreads();
  return red[0] + red[1] + red[2] + red[3];
}

// ---------------------------------------------------------------------------
// K1: normalize key/value/query, circular-convolve (HRR bind), store
// ---------------------------------------------------------------------------
__global__ void prep_kernel(const float* __restrict__ key, const float* __restrict__ value,
                            const float* __restrict__ query, float* __restrict__ Qall,
                            float* __restrict__ qn1, float* __restrict__ bound) {
  const int b = blockIdx.x, t = threadIdx.x;
  __shared__ float kn[256], vn[256], red[4];
  const float kv = key[(size_t)b * 256 + t];
  const float vv = value[(size_t)b * 256 + t];
  const float qv = query[(size_t)b * 256 + t];
  const float sk = block_sum256(kv * kv, red);
  const float sv = block_sum256(vv * vv, red);
  const float sq = block_sum256(qv * qv, red);
  const float knv = kv / (sqrtf(sk) + EPSF);
  const float vnv = vv / (sqrtf(sv) + EPSF);
  const float qnv = qv / (sqrtf(sq) + EPSF);
  kn[t] = knv; vn[t] = vnv;
  qn1[(size_t)b * 256 + t] = qnv;
  // reference re-normalizes inside _topk_idx -> replicate double-normalize
  const float sk2 = block_sum256(knv * knv, red);
  const float sq2 = block_sum256(qnv * qnv, red);
  Qall[(size_t)b * 256 + t] = knv / (sqrtf(sk2) + EPSF);
  Qall[(size_t)(1024 + b) * 256 + t] = qnv / (sqrtf(sq2) + EPSF);
  __syncthreads();
  float acc = 0.f;
  for (int j = 0; j < 256; ++j) acc += kn[j] * vn[(t - j) & 255];
  bound[(size_t)b * 256 + t] = acc;
}

// ---------------------------------------------------------------------------
// Wave-collective bitonic sort of 32 buffered candidates -> keep sorted top-16
// in bV/bI[0..15]; returns new threshold (16th value). Also returns this
// lane's sorted entry (lanes 0..15 valid) via outV/outI.
// ---------------------------------------------------------------------------
__device__ __noinline__ float flush_sort(float* bV, int* bI, int cnt,
                                         float& outV, int& outI) {
  const int lane = threadIdx.x & 63;
  const int l = lane & 31;
  float v = (l < cnt) ? bV[l] : -INFINITY;
  int i = (l < cnt) ? bI[l] : 0x7FFFFFFF;
  #pragma unroll
  for (int k = 2; k <= 32; k <<= 1) {
    #pragma unroll
    for (int d = k >> 1; d >= 1; d >>= 1) {
      const float ov = __shfl_xor(v, d);
      const int oi = __shfl_xor(i, d);
      const bool desc = ((l & k) == 0);
      const bool low = ((l & d) == 0);
      const bool mb = better(v, i, ov, oi);
      const bool keep = desc ? (low ? mb : !mb) : (low ? !mb : mb);
      if (!keep) { v = ov; i = oi; }
    }
  }
  if (lane < 16) { bV[lane] = v; bI[lane] = i; }
  outV = v; outI = i;
  return __shfl(v, 15);
}

// ---------------------------------------------------------------------------
// Rare path: append candidates (>= thr) to the row's LDS buffer via
// ballot/popc rank assignment; flush (sort-32 -> top-16) on overflow.
// Returns possibly-raised threshold.
// ---------------------------------------------------------------------------
__device__ __noinline__ float heavy_append(float c0, float c1, float c2, float c3,
                                           int i0, int i1, int i2, int i3,
                                           float thr, float* bV, int* bI, int* cntp) {
  const int lane = threadIdx.x & 63;
  const unsigned long long ltmask = (1ull << lane) - 1ull;
  int cnt = *cntp;
  float cc[4] = {c0, c1, c2, c3};
  int ii[4] = {i0, i1, i2, i3};
  #pragma unroll
  for (int j = 0; j < 4; ++j) {
    bool f = (cc[j] >= thr);
    unsigned long long m = __ballot(f);
    while (m) {
      const int n = __popcll(m);
      const int freec = 32 - cnt;
      const int rk = __popcll(m & ltmask);
      if (n <= freec) {
        if (f) { bV[cnt + rk] = cc[j]; bI[cnt + rk] = ii[j]; }
        cnt += n;
        m = 0;
      } else {
        if (f && rk < freec) { bV[cnt + rk] = cc[j]; bI[cnt + rk] = ii[j]; f = false; }
        float dv; int di;
        thr = flush_sort(bV, bI, 32, dv, di);
        cnt = 16;
        f = f && (cc[j] >= thr);
        m = __ballot(f);
      }
    }
  }
  if (lane == 0) *cntp = cnt;
  return thr;
}

// ---------------------------------------------------------------------------
// K2: similarities + buffered exact top-16.
// Grid: 1024 = 16 chunks x 64 row-tiles.  Block: 256 thr = 4 waves.
// Block tile: 32 rows x 4096 slots. Wave w: rows (w>>1)*16.., slot half w&1.
// Thread: 4 slots x 16 rows fp32 accumulators.
// ---------------------------------------------------------------------------
__launch_bounds__(256)
__global__ void sims_topk_kernel(const float* __restrict__ Qall,
                                 const float* __restrict__ addr,
                                 float* __restrict__ pv, int* __restrict__ pi) {
  const int bx = blockIdx.x;
  const int chunk = bx >> 6;    // 0..15 (4096 slots each)
  const int rt = bx & 63;       // row tile 0..63 (32 rows each)
  const int t = threadIdx.x;
  const int lane = t & 63;
  const int w = t >> 6;         // wave 0..3
  const int rg = w >> 1;        // row group (16 rows)
  const int sh = w & 1;         // slot half (2048 slots)

  __shared__ float Q[32 * 256];        // 32 KB
  __shared__ float bufV[4][16][32];    // 8 KB
  __shared__ int   bufI[4][16][32];    // 8 KB
  __shared__ int   cnts[4][16];

  {
    const float4* src = (const float4*)(Qall + (size_t)(rt * 32) * 256);
    float4* dst = (float4*)Q;
    #pragma unroll
    for (int i = 0; i < 8; ++i) dst[i * 256 + t] = src[i * 256 + t];
  }
  if (lane < 16) cnts[w][lane] = 0;
  __syncthreads();

  float thrV[16];
  #pragma unroll
  for (int r = 0; r < 16; ++r) thrV[r] = -INFINITY;

  const int sbase0 = chunk * 4096 + sh * 2048;

  #pragma unroll 1
  for (int it = 0; it < 8; ++it) {
    const int sbase = sbase0 + it * 256;
    const float* ap = addr + (size_t)(sbase + lane) * 256;
    float acc[4][16];
    float an[4];
    #pragma unroll
    for (int j = 0; j < 4; ++j) {
      an[j] = 0.f;
      #pragma unroll
      for (int r = 0; r < 16; ++r) acc[j][r] = 0.f;
    }
    for (int d4 = 0; d4 < 64; ++d4) {
      float4 a[4];
      #pragma unroll
      for (int j = 0; j < 4; ++j) a[j] = *(const float4*)(ap + j * (64 * 256) + d4 * 4);
      #pragma unroll
      for (int j = 0; j < 4; ++j)
        an[j] += a[j].x * a[j].x + a[j].y * a[j].y + a[j].z * a[j].z + a[j].w * a[j].w;
      #pragma unroll
      for (int r = 0; r < 16; ++r) {
        const float4 q = *(const float4*)&Q[(rg * 16 + r) * 256 + d4 * 4];
        #pragma unroll
        for (int j = 0; j < 4; ++j)
          acc[j][r] += a[j].x * q.x + a[j].y * q.y + a[j].z * q.z + a[j].w * q.w;
      }
    }
    float rdn[4];
    #pragma unroll
    for (int j = 0; j < 4; ++j) rdn[j] = 1.f / (sqrtf(an[j]) + EPSF);

    #pragma unroll
    for (int r = 0; r < 16; ++r) {
      float c[4]; int ci[4];
      #pragma unroll
      for (int j = 0; j < 4; ++j) { c[j] = acc[j][r] * rdn[j]; ci[j] = sbase + j * 64 + lane; }
      bool any = (c[0] >= thrV[r]) || (c[1] >= thrV[r]) || (c[2] >= thrV[r]) || (c[3] >= thrV[r]);
      if (__ballot(any) != 0ull) {
        thrV[r] = heavy_append(c[0], c[1], c[2], c[3], ci[0], ci[1], ci[2], ci[3],
                               thrV[r], &bufV[w][r][0], &bufI[w][r][0], &cnts[w][r]);
      }
    }
  }

  // final per-wave flush: buf[0..15] = sorted top-16 of this wave's stream
  #pragma unroll 1
  for (int r = 0; r < 16; ++r) {
    float dv; int di;
    flush_sort(&bufV[w][r][0], &bufI[w][r][0], cnts[w][r], dv, di);
  }
  __syncthreads();

  // waves sh==0 merge partner wave's 16 into their buffer -> exact chunk top-16
  if (sh == 0) {
    #pragma unroll 1
    for (int r = 0; r < 16; ++r) {
      if (lane < 16) {
        bufV[w][r][16 + lane] = bufV[w + 1][r][lane];
        bufI[w][r][16 + lane] = bufI[w + 1][r][lane];
      }
      asm volatile("s_waitcnt lgkmcnt(0)" ::: "memory");
      float sv; int si;
      flush_sort(&bufV[w][r][0], &bufI[w][r][0], 32, sv, si);
      const int grow = rt * 32 + rg * 16 + r;
      if (lane < 16) {
        pv[(size_t)grow * 256 + chunk * 16 + lane] = sv;
        pi[(size_t)grow * 256 + chunk * 16 + lane] = si;
      }
    }
  }
}

// ---------------------------------------------------------------------------
// K3: merge 16 chunk-partials (256 candidates) -> final top-16 per row.
// One wave per row; 4 candidates per lane.
// ---------------------------------------------------------------------------
__global__ void merge_topk_kernel(const float* __restrict__ pv, const int* __restrict__ pi,
                                  int* __restrict__ fidx) {
  const int row = blockIdx.x;
  const int lane = threadIdx.x; // 64 threads
  float v[4]; int ix[4];
  #pragma unroll
  for (int j = 0; j < 4; ++j) {
    v[j] = pv[(size_t)row * 256 + j * 64 + lane];
    ix[j] = pi[(size_t)row * 256 + j * 64 + lane];
  }
  for (int s = 0; s < 16; ++s) {
    float bv = v[0]; int bi = ix[0];
    #pragma unroll
    for (int j = 1; j < 4; ++j) if (better(v[j], ix[j], bv, bi)) { bv = v[j]; bi = ix[j]; }
    #pragma unroll
    for (int m = 1; m < 64; m <<= 1) {
      const float ov = __shfl_xor(bv, m); const int oi = __shfl_xor(bi, m);
      if (better(ov, oi, bv, bi)) { bv = ov; bi = oi; }
    }
    if (lane == 0) fidx[(size_t)row * 16 + s] = bi;
    #pragma unroll
    for (int j = 0; j < 4; ++j) if (ix[j] == bi) v[j] = -INFINITY; // ids unique
  }
}

// ---------------------------------------------------------------------------
// K4: content gather (decayed memory + write-hits via bitset join),
//     unbind via direct 256-pt DFT (Wiener division), normalize, store.
// ---------------------------------------------------------------------------
__global__ void finalize_kernel(const float* __restrict__ qn1,
                                const float* __restrict__ bound,
                                const int* __restrict__ fidx,
                                const float* __restrict__ mem,
                                float* __restrict__ out) {
  const int b = blockIdx.x, t = threadIdx.x;
  __shared__ unsigned int bs[2048];   // 65536-bit slot bitset
  __shared__ float cont[256], qn[256];
  __shared__ float Br[129], Bi[129];
  __shared__ float2 tw[256];
  __shared__ int ri[16];
  __shared__ int hits[1024];
  __shared__ int hcnt;
  __shared__ float red[4];

  {
    const double ang = (6.283185307179586476925286766559 / 256.0) * (double)t;
    tw[t] = make_float2((float)cos(ang), (float)sin(ang));
  }
  #pragma unroll
  for (int i = 0; i < 8; ++i) bs[t + i * 256] = 0u;
  if (t == 0) hcnt = 0;
  qn[t] = qn1[(size_t)b * 256 + t];
  if (t < 16) ri[t] = fidx[(size_t)(1024 + b) * 16 + t]; // read slots
  __syncthreads();
  if (t < 16) atomicOr(&bs[ri[t] >> 5], 1u << (ri[t] & 31));
  __syncthreads();

  float c = 0.f;
  #pragma unroll
  for (int k = 0; k < 16; ++k) c += mem[(size_t)ri[k] * 256 + t];
  c *= 0.995f;

  for (int e = t; e < 16384; e += 256) {
    const int s = fidx[e]; // rows 0..1023 of fidx = idx_w
    if ((bs[s >> 5] >> (s & 31)) & 1u) {
      const int p = atomicAdd(&hcnt, 1);
      if (p < 1024) hits[p] = e;
    }
  }
  __syncthreads();
  int hn = hcnt; if (hn > 1024) hn = 1024;
  if (t == 0) {
    for (int i = 1; i < hn; ++i) {
      const int x = hits[i]; int j2 = i - 1;
      while (j2 >= 0 && hits[j2] > x) { hits[j2 + 1] = hits[j2]; --j2; }
      hits[j2 + 1] = x;
    }
  }
  __syncthreads();
  for (int h = 0; h < hn; ++h) c += bound[(size_t)(hits[h] >> 4) * 256 + t];
  cont[t] = c;
  __syncthreads();

  if (t < 129) {
    float ar = 0.f, ai = 0.f, cr2 = 0.f, ci2 = 0.f;
    for (int n = 0; n < 256; ++n) {
      const float2 wv = tw[(t * n) & 255];
      const float qv = qn[n], cv = cont[n];
      ar += qv * wv.x; ai -= qv * wv.y;
      cr2 += cv * wv.x; ci2 -= cv * wv.y;
    }
    const float den = ar * ar + ai * ai + 1e-8f;
    Br[t] = (cr2 * ar + ci2 * ai) / den;
    Bi[t] = (ci2 * ar - cr2 * ai) / den;
  }
  __syncthreads();

  float o = Br[0] + ((t & 1) ? -Br[128] : Br[128]);
  for (int k = 1; k < 128; ++k) {
    const float2 wv = tw[(k * t) & 255];
    o += 2.f * (Br[k] * wv.x - Bi[k] * wv.y);
  }
  o *= (1.f / 256.f);

  const float ss2 = block_sum256(o * o, red);
  out[(size_t)b * 256 + t] = o / (sqrtf(ss2) + EPSF);
}

// ---------------------------------------------------------------------------
extern "C" void kernel_launch(void* const* d_in, const int* in_sizes, int n_in,
                              void* d_out, int out_size, void* d_ws, size_t ws_size,
                              hipStream_t stream) {
  const float* key    = (const float*)d_in[0];
  const float* value  = (const float*)d_in[1];
  const float* query  = (const float*)d_in[2];
  const float* addr   = (const float*)d_in[3];
  const float* memory = (const float*)d_in[4];
  float* out = (float*)d_out;

  char* ws = (char*)d_ws;
  float* Qall  = (float*)(ws + 0);          // 2048*256*4 = 2 MB
  float* qn1   = (float*)(ws + (2u << 20)); // 1 MB
  float* bound = (float*)(ws + (3u << 20)); // 1 MB
  float* pv    = (float*)(ws + (4u << 20)); // 2048*256*4 = 2 MB
  int*   pi    = (int*)  (ws + (6u << 20)); // 2 MB
  int*   fidx  = (int*)  (ws + (8u << 20)); // 128 KB

  prep_kernel<<<1024, 256, 0, stream>>>(key, value, query, Qall, qn1, bound);
  sims_topk_kernel<<<1024, 256, 0, stream>>>(Qall, addr, pv, pi);
  merge_topk_kernel<<<2048, 64, 0, stream>>>(pv, pi, fidx);
  finalize_kernel<<<1024, 256, 0, stream>>>(qn1, bound, fidx, memory, out);
}